// Round 8
// baseline (198.174 us; speedup 1.0000x reference)
//
#include <hip/hip_runtime.h>

typedef float fvec4 __attribute__((ext_vector_type(4)));

#define NN 65536      // total nodes per side (B*NPG)
#define EE 1048576    // edges per side (B*NPG*DEG)
#define BB 128
#define NPG 512
#define EPG 8192      // edges per graph (NPG*DEG)

// ---- xW chunk (16 outputs) from register-resident input row ----
template <int FIN, int FOUT>
__device__ __forceinline__ void compute_acc_regs(const float* xin, const float* __restrict__ w,
                                                 int c, fvec4 (&acc)[4]) {
#pragma unroll
  for (int q = 0; q < 4; ++q) acc[q] = fvec4{0.f, 0.f, 0.f, 0.f};
  const float* wc = w + c * 16;
#pragma unroll
  for (int k = 0; k < FIN; ++k) {
    const fvec4* wr = reinterpret_cast<const fvec4*>(wc + (size_t)k * FOUT);
    const float xk = xin[k];
#pragma unroll
    for (int q = 0; q < 4; ++q) acc[q] += xk * wr[q];
  }
}

// ---- publish + gather with bank-GROUP-uniform swizzled quad layout ----
// line = 2 rows = 32 words; quad q of row r -> slot (q + 4*(r&1) + ((r>>1)&7)) & 7
// of line r>>1. Bijective per line; uniform over bank groups for random rows.
// sids holds packed keys: (line<<4) | m, with m = ((r&1)<<2) + ((r>>1)&7).
// Produces o[4] = aggregated output chunk (valid when !LAST || slot>=0).
template <int FOUT, bool RELU, bool LAST>
__device__ __forceinline__ void agg_chunk(const fvec4 (&acc)[4], fvec4 (&o)[4], int c,
                                          const float* __restrict__ bias,
                                          int start, int count, float inv_v, int slot,
                                          fvec4* __restrict__ msgQ, const int* __restrict__ sids,
                                          float* __restrict__ hs, int hb) {
  const int v = threadIdx.x;
  {
    const int lb = (v >> 1) << 3;
    const int m = ((v & 1) << 2) + ((v >> 1) & 7);
#pragma unroll
    for (int q = 0; q < 4; ++q) msgQ[lb + ((q + m) & 7)] = acc[q] * inv_v;
  }
  __syncthreads();
  if (!LAST || slot >= 0) {
    fvec4 s0 = {0.f, 0.f, 0.f, 0.f}, s1 = s0, s2 = s0, s3 = s0;
    int e = start;
    const int end = start + count;
#define ACC_EDGE(P) { const int m_ = (P) & 15; const int l_ = ((P) >> 4) << 3;       \
      s0 += msgQ[l_ + (m_ & 7)];       s1 += msgQ[l_ + ((1 + m_) & 7)];              \
      s2 += msgQ[l_ + ((2 + m_) & 7)]; s3 += msgQ[l_ + ((3 + m_) & 7)]; }
    for (; e + 2 <= end; e += 2) {
      const int a0 = sids[e], a1 = sids[e + 1];
      ACC_EDGE(a0) ACC_EDGE(a1)
    }
    if (e < end) { const int a0 = sids[e]; ACC_EDGE(a0) }
#undef ACC_EDGE
    fvec4 sArr[4] = {s0, s1, s2, s3};
    const float i2 = inv_v * inv_v;
#pragma unroll
    for (int q = 0; q < 4; ++q) {
#pragma unroll
      for (int j = 0; j < 4; ++j) {
        float ov = sArr[q][j] * inv_v + acc[q][j] * i2 + bias[c * 16 + q * 4 + j];
        if (RELU) ov = fmaxf(ov, 0.f);
        o[q][j] = ov;
      }
    }
    if (slot >= 0) {
      fvec4* hp = reinterpret_cast<fvec4*>(hs + ((size_t)hb + slot) * FOUT + c * 16);
#pragma unroll
      for (int q = 0; q < 4; ++q) hp[q] = o[q];
    }
  }
  __syncthreads();
}

// ---------------- one block per (side, graph): CSR build in LDS + 3 GCN layers ----------------
// Fused-GEMM trick: as each h0 chunk is produced, fold it into y1 = h0*W1 (and h1
// chunks into y2 = h1*W2), so h0/h1 never persist in registers. Layer-1/2 publish
// reads y1/y2 slices directly (their xW is already computed).
__global__ __launch_bounds__(512)
__attribute__((amdgpu_waves_per_eu(1, 2)))
void k_all(const float* __restrict__ x_i, const float* __restrict__ x_j,
           const float* __restrict__ gw0, const float* __restrict__ gb0,
           const float* __restrict__ gw1, const float* __restrict__ gb1,
           const float* __restrict__ gw2, const float* __restrict__ gb2,
           const int* __restrict__ ei, const int* __restrict__ ej,
           float* __restrict__ hs0, float* __restrict__ hs1, float* __restrict__ hs2) {
  __shared__ int sids[EPG];             // 32 KB: packed swizzle keys, bucketed by dst
  __shared__ fvec4 msgQ[8 * (NPG / 2)]; // 32 KB: swizzled-quad message buffer (aliases dsts in prep)
  __shared__ int cnt[NPG];
  __shared__ int posb[NPG];
  __shared__ int wsum[8];
  int* const dsts = reinterpret_cast<int*>(msgQ);  // prep-only staging

  const int side = blockIdx.x >> 7;
  const int g = blockIdx.x & 127;
  const float* __restrict__ x = side ? x_j : x_i;
  const int* __restrict__ eidx = side ? ej : ei;
  const int v = threadIdx.x;
  const int base = g * NPG;
  const int ebase = g * EPG;

  // ---- in-LDS degree count ----
  cnt[v] = 0;
  __syncthreads();
  for (int k = v; k < EPG; k += 512) {
    int d = eidx[EE + ebase + k] - base;
    dsts[k] = d;
    atomicAdd(&cnt[d], 1);
  }
  __syncthreads();

  // ---- in-block exclusive scan over 512 counts ----
  const int count = cnt[v];
  int xa = count;
  const int lane = v & 63;
#pragma unroll
  for (int d = 1; d < 64; d <<= 1) {
    int y = __shfl_up(xa, d, 64);
    if (lane >= d) xa += y;
  }
  const int wid = v >> 6;
  if (lane == 63) wsum[wid] = xa;
  __syncthreads();
  if (v == 0) {
    int a = 0;
#pragma unroll
    for (int i = 0; i < 8; ++i) { int tv = wsum[i]; wsum[i] = a; a += tv; }
  }
  __syncthreads();
  const int start = xa - count + wsum[wid];
  posb[v] = start;
  const float inv_v = rsqrtf((float)count + 1.0f);
  __syncthreads();

  // ---- CSR fill (bucket by dst), storing pre-swizzled packed keys ----
  for (int k = v; k < EPG; k += 512) {
    int sv = eidx[ebase + k] - base;
    int p = atomicAdd(&posb[dsts[k]], 1);
    int line = sv >> 1;
    int m = ((sv & 1) << 2) + (line & 7);
    sids[p] = (line << 4) | m;
  }

  // ---- load this node's input row (flies during the barrier) ----
  float xin[64];
  {
    const fvec4* xv = reinterpret_cast<const fvec4*>(x + (size_t)(base + v) * 64);
#pragma unroll
    for (int k4 = 0; k4 < 16; ++k4) {
      fvec4 tv = xv[k4];
#pragma unroll
      for (int j = 0; j < 4; ++j) xin[4 * k4 + j] = tv[j];
    }
  }
  __syncthreads();

  // ---- sampled rows used by the bilinear-resized similarity image ----
  constexpr int srows[20] = {25, 26, 76, 77, 127, 128, 178, 179, 229, 230,
                             281, 282, 332, 333, 383, 384, 434, 435, 485, 486};
  int slot = -1;
#pragma unroll
  for (int i = 0; i < 20; ++i)
    if (v == srows[i]) slot = i;
  const int hb = (side * BB + g) * 20;

  // ---- layer 0 (4 chunks), folding h0 chunks into y1 = h0*W1 ----
  fvec4 y1v[8];
#pragma unroll
  for (int q = 0; q < 8; ++q) y1v[q] = fvec4{0.f, 0.f, 0.f, 0.f};
#pragma unroll
  for (int c = 0; c < 4; ++c) {
    fvec4 acc[4], o[4];
    compute_acc_regs<64, 64>(xin, gw0, c, acc);
    agg_chunk<64, true, false>(acc, o, c, gb0, start, count, inv_v, slot, msgQ, sids, hs0, hb);
#pragma unroll
    for (int f = 0; f < 16; ++f) {
      const float hf = o[f >> 2][f & 3];
      const fvec4* wr = reinterpret_cast<const fvec4*>(gw1 + (size_t)(16 * c + f) * 32);
#pragma unroll
      for (int q = 0; q < 8; ++q) y1v[q] += hf * wr[q];
    }
  }

  // ---- layer 1 (2 chunks): xW already in y1v; fold h1 chunks into y2 = h1*W2 ----
  fvec4 y2v[4];
#pragma unroll
  for (int q = 0; q < 4; ++q) y2v[q] = fvec4{0.f, 0.f, 0.f, 0.f};
#pragma unroll
  for (int c = 0; c < 2; ++c) {
    fvec4 acc[4], o[4];
#pragma unroll
    for (int q = 0; q < 4; ++q) acc[q] = y1v[4 * c + q];
    agg_chunk<32, true, false>(acc, o, c, gb1, start, count, inv_v, slot, msgQ, sids, hs1, hb);
#pragma unroll
    for (int f = 0; f < 16; ++f) {
      const float hf = o[f >> 2][f & 3];
      const fvec4* wr = reinterpret_cast<const fvec4*>(gw2 + (size_t)(16 * c + f) * 16);
#pragma unroll
      for (int q = 0; q < 4; ++q) y2v[q] += hf * wr[q];
    }
  }

  // ---- layer 2 (1 chunk): xW already in y2v; gather only for sampled rows ----
  {
    fvec4 o[4];
    agg_chunk<16, false, true>(y2v, o, 0, gb2, start, count, inv_v, slot, msgQ, sids, hs2, hb);
  }
}

// ---------------- head: sampled sim -> bilinear 10x10 -> conv3x3(1->8) -> MLP -> sigmoid ----------------
__global__ __launch_bounds__(256) void k_head(const float* __restrict__ hs0, const float* __restrict__ hs1,
                                              const float* __restrict__ hs2,
                                              const float* __restrict__ cw0, const float* __restrict__ cb0,
                                              const float* __restrict__ cw1, const float* __restrict__ cb1,
                                              const float* __restrict__ cw2, const float* __restrict__ cb2,
                                              const float* __restrict__ mw0, const float* __restrict__ mb0,
                                              const float* __restrict__ mw1, const float* __restrict__ mb1,
                                              const float* __restrict__ mw2, const float* __restrict__ mb2,
                                              const float* __restrict__ mw3, const float* __restrict__ mb3,
                                              const float* __restrict__ mw4, const float* __restrict__ mb4,
                                              const float* __restrict__ sw, const float* __restrict__ sb,
                                              float* __restrict__ out) {
  __shared__ float hi[2240];  // 20*64 + 20*32 + 20*16
  __shared__ float hj[2240];
  __shared__ float sim[400];
  __shared__ float simr[100];
  __shared__ float feat[2400];
  __shared__ float red[256];
  __shared__ float mbuf[60];
  const int b = blockIdx.x, t = threadIdx.x;

  for (int k = t; k < 1280; k += 256) {
    hi[k] = hs0[(size_t)(0 * BB + b) * 1280 + k];
    hj[k] = hs0[(size_t)(1 * BB + b) * 1280 + k];
  }
  for (int k = t; k < 640; k += 256) {
    hi[1280 + k] = hs1[(size_t)(0 * BB + b) * 640 + k];
    hj[1280 + k] = hs1[(size_t)(1 * BB + b) * 640 + k];
  }
  for (int k = t; k < 320; k += 256) {
    hi[1920 + k] = hs2[(size_t)(0 * BB + b) * 320 + k];
    hj[1920 + k] = hs2[(size_t)(1 * BB + b) * 320 + k];
  }
  __syncthreads();

  const int Fs[3] = {64, 32, 16};
  const int HOFF[3] = {0, 1280, 1920};
  const float* CW[3] = {cw0, cw1, cw2};
  const float* CB[3] = {cb0, cb1, cb2};

  for (int li = 0; li < 3; ++li) {
    const int F = Fs[li];
    const float* Hi = hi + HOFF[li];
    const float* Hj = hj + HOFF[li];
    for (int p = t; p < 400; p += 256) {
      int r = p / 20, cq = p % 20;
      float a = 0.0f;
      for (int d = 0; d < F; ++d) a += Hi[r * F + d] * Hj[cq * F + d];
      sim[p] = a;
    }
    __syncthreads();
    if (t < 100) {
      int oy = t / 10, ox = t % 10;
      float cy = (oy + 0.5f) * (512.0f / 10.0f) - 0.5f;
      float cx = (ox + 0.5f) * (512.0f / 10.0f) - 0.5f;
      float fy = cy - floorf(cy);
      float fx = cx - floorf(cx);
      int r0 = 2 * oy, c0 = 2 * ox;
      float s00 = sim[r0 * 20 + c0], s01 = sim[r0 * 20 + c0 + 1];
      float s10 = sim[(r0 + 1) * 20 + c0], s11 = sim[(r0 + 1) * 20 + c0 + 1];
      simr[t] = (1.0f - fy) * ((1.0f - fx) * s00 + fx * s01) + fy * ((1.0f - fx) * s10 + fx * s11);
    }
    __syncthreads();
    const float* cw = CW[li];
    const float* cb = CB[li];
    for (int idx = t; idx < 800; idx += 256) {
      int cch = idx / 100, rem = idx % 100, y = rem / 10, x = rem % 10;
      float a = cb[cch];
#pragma unroll
      for (int ky = 0; ky < 3; ++ky) {
#pragma unroll
        for (int kx = 0; kx < 3; ++kx) {
          int iy = y + ky - 1, ix = x + kx - 1;
          if (iy >= 0 && iy < 10 && ix >= 0 && ix < 10)
            a += cw[cch * 9 + ky * 3 + kx] * simr[iy * 10 + ix];
        }
      }
      feat[li * 800 + idx] = fmaxf(a, 0.0f);
    }
    __syncthreads();
  }

  // MLP0: 2400 -> 32, 8 partial sums per output
  {
    int f = t & 31, part = t >> 5;
    float a = 0.0f;
    int k0 = part * 300;
    for (int k = k0; k < k0 + 300; ++k) a += feat[k] * mw0[k * 32 + f];
    red[t] = a;
    __syncthreads();
    if (t < 32) {
      float s = mb0[t];
#pragma unroll
      for (int p = 0; p < 8; ++p) s += red[p * 32 + t];
      mbuf[t] = fmaxf(s, 0.0f);
    }
    __syncthreads();
  }
  if (t < 16) {
    float s = mb1[t];
    for (int k = 0; k < 32; ++k) s += mbuf[k] * mw1[k * 16 + t];
    mbuf[32 + t] = fmaxf(s, 0.0f);
  }
  __syncthreads();
  if (t < 8) {
    float s = mb2[t];
    for (int k = 0; k < 16; ++k) s += mbuf[32 + k] * mw2[k * 8 + t];
    mbuf[48 + t] = fmaxf(s, 0.0f);
  }
  __syncthreads();
  if (t < 4) {
    float s = mb3[t];
    for (int k = 0; k < 8; ++k) s += mbuf[48 + k] * mw3[k * 4 + t];
    mbuf[56 + t] = fmaxf(s, 0.0f);
  }
  __syncthreads();
  if (t == 0) {
    float s = mb4[0];
    for (int k = 0; k < 4; ++k) s += mbuf[56 + k] * mw4[k];
    s = fmaxf(s, 0.0f);
    float z = s * sw[0] + sb[0];
    out[b] = 1.0f / (1.0f + expf(-z));
  }
}

extern "C" void kernel_launch(void* const* d_in, const int* in_sizes, int n_in,
                              void* d_out, int out_size, void* d_ws, size_t ws_size,
                              hipStream_t stream) {
  (void)in_sizes; (void)n_in; (void)out_size; (void)ws_size;
  const float* x_i = (const float*)d_in[0];
  const float* x_j = (const float*)d_in[1];
  const float* gw0 = (const float*)d_in[2];
  const float* gb0 = (const float*)d_in[3];
  const float* gw1 = (const float*)d_in[4];
  const float* gb1 = (const float*)d_in[5];
  const float* gw2 = (const float*)d_in[6];
  const float* gb2 = (const float*)d_in[7];
  const float* cw0 = (const float*)d_in[8];
  const float* cb0 = (const float*)d_in[9];
  const float* cw1 = (const float*)d_in[10];
  const float* cb1 = (const float*)d_in[11];
  const float* cw2 = (const float*)d_in[12];
  const float* cb2 = (const float*)d_in[13];
  const float* mw0 = (const float*)d_in[14];
  const float* mb0 = (const float*)d_in[15];
  const float* mw1 = (const float*)d_in[16];
  const float* mb1 = (const float*)d_in[17];
  const float* mw2 = (const float*)d_in[18];
  const float* mb2 = (const float*)d_in[19];
  const float* mw3 = (const float*)d_in[20];
  const float* mb3 = (const float*)d_in[21];
  const float* mw4 = (const float*)d_in[22];
  const float* mb4 = (const float*)d_in[23];
  const float* scw = (const float*)d_in[24];
  const float* scb = (const float*)d_in[25];
  const int* ei = (const int*)d_in[26];
  const int* ej = (const int*)d_in[27];
  float* out = (float*)d_out;

  char* p = (char*)d_ws;
  auto take = [&](size_t bytes) {
    char* r = p;
    p += (bytes + 255) & ~(size_t)255;
    return r;
  };
  float* hs0 = (float*)take((size_t)2 * BB * 20 * 64 * 4);
  float* hs1 = (float*)take((size_t)2 * BB * 20 * 32 * 4);
  float* hs2 = (float*)take((size_t)2 * BB * 20 * 16 * 4);

  k_all<<<2 * BB, 512, 0, stream>>>(x_i, x_j, gw0, gb0, gw1, gb1, gw2, gb2,
                                    ei, ej, hs0, hs1, hs2);
  k_head<<<BB, 256, 0, stream>>>(hs0, hs1, hs2, cw0, cb0, cw1, cb1, cw2, cb2,
                                 mw0, mb0, mw1, mb1, mw2, mb2, mw3, mb3, mw4, mb4,
                                 scw, scb, out);
}

// Round 12
// 140.741 us; speedup vs baseline: 1.4081x; 1.4081x over previous
//
#include <hip/hip_runtime.h>

typedef float fvec4 __attribute__((ext_vector_type(4)));

#define NN 65536      // total nodes per side (B*NPG)
#define EE 1048576    // edges per side (B*NPG*DEG)
#define BB 128
#define NPG 512
#define EPG 8192      // edges per graph (NPG*DEG)

// ---- publish + gather with bank-GROUP-uniform swizzled quad layout ----
// line = 2 rows = 32 words; quad q of row r -> slot (q + 4*(r&1) + ((r>>1)&7)) & 7
// of line r>>1. Bijective per line; uniform over bank groups for random rows.
// sids holds packed keys: (line<<4) | m, with m = ((r&1)<<2) + ((r>>1)&7).
// o[] gets the aggregated+combined output chunk (valid when !LAST || slot>=0).
template <int FOUT, bool RELU, bool LAST>
__device__ __forceinline__ void agg_chunk(const fvec4 (&acc)[4], fvec4 (&o)[4], int c,
                                          const float* __restrict__ bias,
                                          int start, int count, float inv_v, int slot,
                                          fvec4* __restrict__ msgQ, const int* __restrict__ sids,
                                          float* __restrict__ hs, int hb) {
  const int v = threadIdx.x;
  {
    const int lb = (v >> 1) << 3;
    const int m = ((v & 1) << 2) + ((v >> 1) & 7);
#pragma unroll
    for (int q = 0; q < 4; ++q) msgQ[lb + ((q + m) & 7)] = acc[q] * inv_v;
  }
  __syncthreads();
  if (!LAST || slot >= 0) {
    fvec4 s0 = {0.f, 0.f, 0.f, 0.f}, s1 = s0, s2 = s0, s3 = s0;
    int e = start;
    const int end = start + count;
#define ACC_EDGE(P) { const int m_ = (P) & 15; const int l_ = ((P) >> 4) << 3;       \
      s0 += msgQ[l_ + (m_ & 7)];       s1 += msgQ[l_ + ((1 + m_) & 7)];              \
      s2 += msgQ[l_ + ((2 + m_) & 7)]; s3 += msgQ[l_ + ((3 + m_) & 7)]; }
    for (; e + 2 <= end; e += 2) {
      const int a0 = sids[e], a1 = sids[e + 1];
      ACC_EDGE(a0) ACC_EDGE(a1)
    }
    if (e < end) { const int a0 = sids[e]; ACC_EDGE(a0) }
#undef ACC_EDGE
    fvec4 sArr[4] = {s0, s1, s2, s3};
    const float i2 = inv_v * inv_v;
#pragma unroll
    for (int q = 0; q < 4; ++q) {
#pragma unroll
      for (int j = 0; j < 4; ++j) {
        float ov = sArr[q][j] * inv_v + acc[q][j] * i2 + bias[c * 16 + q * 4 + j];
        if (RELU) ov = fmaxf(ov, 0.f);
        o[q][j] = ov;
      }
    }
    if (slot >= 0) {
      fvec4* hp = reinterpret_cast<fvec4*>(hs + ((size_t)hb + slot) * FOUT + c * 16);
#pragma unroll
      for (int q = 0; q < 4; ++q) hp[q] = o[q];
    }
  }
  __syncthreads();
}

// ---------------- one block per (side, graph): CSR build in LDS + 3 GCN layers ----------------
// Register plan (fits 128 VGPRs, no spills):
//  - layer-0 xW computed in ONE streaming pass over x into a0[16] (64 regs);
//    x is never stored (4 fvec4 in flight), read exactly once from global.
//  - as each h0 chunk completes (post-gather) it's folded into y1=h0*W1 (32 regs,
//    born AFTER the widest point) and its a0 chunk dies; same for y2=h1*W2.
__global__ __launch_bounds__(512)
void k_all(const float* __restrict__ x_i, const float* __restrict__ x_j,
           const float* __restrict__ gw0, const float* __restrict__ gb0,
           const float* __restrict__ gw1, const float* __restrict__ gb1,
           const float* __restrict__ gw2, const float* __restrict__ gb2,
           const int* __restrict__ ei, const int* __restrict__ ej,
           float* __restrict__ hs0, float* __restrict__ hs1, float* __restrict__ hs2) {
  __shared__ int sids[EPG];             // 32 KB: packed swizzle keys, bucketed by dst
  __shared__ fvec4 msgQ[8 * (NPG / 2)]; // 32 KB: swizzled-quad message buffer (aliases dsts in prep)
  __shared__ int cnt[NPG];
  __shared__ int posb[NPG];
  __shared__ int wsum[8];
  int* const dsts = reinterpret_cast<int*>(msgQ);  // prep-only staging

  const int side = blockIdx.x >> 7;
  const int g = blockIdx.x & 127;
  const float* __restrict__ x = side ? x_j : x_i;
  const int* __restrict__ eidx = side ? ej : ei;
  const int v = threadIdx.x;
  const int base = g * NPG;
  const int ebase = g * EPG;

  // ---- in-LDS degree count ----
  cnt[v] = 0;
  __syncthreads();
  for (int k = v; k < EPG; k += 512) {
    int d = eidx[EE + ebase + k] - base;
    dsts[k] = d;
    atomicAdd(&cnt[d], 1);
  }
  __syncthreads();

  // ---- in-block exclusive scan over 512 counts ----
  const int count = cnt[v];
  int xa = count;
  const int lane = v & 63;
#pragma unroll
  for (int d = 1; d < 64; d <<= 1) {
    int y = __shfl_up(xa, d, 64);
    if (lane >= d) xa += y;
  }
  const int wid = v >> 6;
  if (lane == 63) wsum[wid] = xa;
  __syncthreads();
  if (v == 0) {
    int a = 0;
#pragma unroll
    for (int i = 0; i < 8; ++i) { int tv = wsum[i]; wsum[i] = a; a += tv; }
  }
  __syncthreads();
  const int start = xa - count + wsum[wid];
  posb[v] = start;
  const float inv_v = rsqrtf((float)count + 1.0f);
  __syncthreads();

  // ---- CSR fill (bucket by dst), storing pre-swizzled packed keys ----
  for (int k = v; k < EPG; k += 512) {
    int sv = eidx[ebase + k] - base;
    int p = atomicAdd(&posb[dsts[k]], 1);
    int line = sv >> 1;
    int m = ((sv & 1) << 2) + (line & 7);
    sids[p] = (line << 4) | m;
  }
  __syncthreads();

  // ---- sampled rows used by the bilinear-resized similarity image ----
  constexpr int srows[20] = {25, 26, 76, 77, 127, 128, 178, 179, 229, 230,
                             281, 282, 332, 333, 383, 384, 434, 435, 485, 486};
  int slot = -1;
#pragma unroll
  for (int i = 0; i < 20; ++i)
    if (v == srows[i]) slot = i;
  const int hb = (side * BB + g) * 20;

  // ---- layer 0: full xW0 row in one streaming pass over x ----
  fvec4 a0[16];
#pragma unroll
  for (int q = 0; q < 16; ++q) a0[q] = fvec4{0.f, 0.f, 0.f, 0.f};
  {
    const fvec4* xv = reinterpret_cast<const fvec4*>(x + (size_t)(base + v) * 64);
#pragma unroll 1
    for (int k16 = 0; k16 < 4; ++k16) {
      fvec4 xq[4];
#pragma unroll
      for (int u = 0; u < 4; ++u) xq[u] = xv[4 * k16 + u];
#pragma unroll
      for (int u = 0; u < 4; ++u) {
#pragma unroll
        for (int j = 0; j < 4; ++j) {
          const float xk = xq[u][j];
          const fvec4* wr = reinterpret_cast<const fvec4*>(gw0 + (size_t)(16 * k16 + 4 * u + j) * 64);
#pragma unroll
          for (int q = 0; q < 16; ++q) a0[q] += xk * wr[q];
        }
      }
    }
  }

  // ---- layer-0 chunks: publish/gather from a0, fold h0 chunks into y1 ----
  fvec4 y1[8];
#pragma unroll
  for (int c = 0; c < 4; ++c) {
    fvec4 acc[4], o[4];
#pragma unroll
    for (int q = 0; q < 4; ++q) acc[q] = a0[4 * c + q];
    agg_chunk<64, true, false>(acc, o, c, gb0, start, count, inv_v, slot, msgQ, sids, hs0, hb);
    if (c == 0) {
#pragma unroll
      for (int q = 0; q < 8; ++q) y1[q] = fvec4{0.f, 0.f, 0.f, 0.f};
    }
#pragma unroll
    for (int f = 0; f < 16; ++f) {
      const float hf = o[f >> 2][f & 3];
      const fvec4* wr = reinterpret_cast<const fvec4*>(gw1 + (size_t)(16 * c + f) * 32);
#pragma unroll
      for (int q = 0; q < 8; ++q) y1[q] += hf * wr[q];
    }
  }

  // ---- layer-1 chunks: publish/gather from y1, fold h1 chunks into y2 ----
  fvec4 y2[4];
#pragma unroll
  for (int c = 0; c < 2; ++c) {
    fvec4 acc[4], o[4];
#pragma unroll
    for (int q = 0; q < 4; ++q) acc[q] = y1[4 * c + q];
    agg_chunk<32, true, false>(acc, o, c, gb1, start, count, inv_v, slot, msgQ, sids, hs1, hb);
    if (c == 0) {
#pragma unroll
      for (int q = 0; q < 4; ++q) y2[q] = fvec4{0.f, 0.f, 0.f, 0.f};
    }
#pragma unroll
    for (int f = 0; f < 16; ++f) {
      const float hf = o[f >> 2][f & 3];
      const fvec4* wr = reinterpret_cast<const fvec4*>(gw2 + (size_t)(16 * c + f) * 16);
#pragma unroll
      for (int q = 0; q < 4; ++q) y2[q] += hf * wr[q];
    }
  }

  // ---- layer 2: publish from y2; gather only for sampled rows ----
  {
    fvec4 o[4];
    agg_chunk<16, false, true>(y2, o, 0, gb2, start, count, inv_v, slot, msgQ, sids, hs2, hb);
  }
}

// ---------------- head: sampled sim -> bilinear 10x10 -> conv3x3(1->8) -> MLP -> sigmoid ----------------
__global__ __launch_bounds__(256) void k_head(const float* __restrict__ hs0, const float* __restrict__ hs1,
                                              const float* __restrict__ hs2,
                                              const float* __restrict__ cw0, const float* __restrict__ cb0,
                                              const float* __restrict__ cw1, const float* __restrict__ cb1,
                                              const float* __restrict__ cw2, const float* __restrict__ cb2,
                                              const float* __restrict__ mw0, const float* __restrict__ mb0,
                                              const float* __restrict__ mw1, const float* __restrict__ mb1,
                                              const float* __restrict__ mw2, const float* __restrict__ mb2,
                                              const float* __restrict__ mw3, const float* __restrict__ mb3,
                                              const float* __restrict__ mw4, const float* __restrict__ mb4,
                                              const float* __restrict__ sw, const float* __restrict__ sb,
                                              float* __restrict__ out) {
  __shared__ float hi[2240];  // 20*64 + 20*32 + 20*16
  __shared__ float hj[2240];
  __shared__ float sim[400];
  __shared__ float simr[100];
  __shared__ float feat[2400];
  __shared__ float red[256];
  __shared__ float mbuf[60];
  const int b = blockIdx.x, t = threadIdx.x;

  for (int k = t; k < 1280; k += 256) {
    hi[k] = hs0[(size_t)(0 * BB + b) * 1280 + k];
    hj[k] = hs0[(size_t)(1 * BB + b) * 1280 + k];
  }
  for (int k = t; k < 640; k += 256) {
    hi[1280 + k] = hs1[(size_t)(0 * BB + b) * 640 + k];
    hj[1280 + k] = hs1[(size_t)(1 * BB + b) * 640 + k];
  }
  for (int k = t; k < 320; k += 256) {
    hi[1920 + k] = hs2[(size_t)(0 * BB + b) * 320 + k];
    hj[1920 + k] = hs2[(size_t)(1 * BB + b) * 320 + k];
  }
  __syncthreads();

  const int Fs[3] = {64, 32, 16};
  const int HOFF[3] = {0, 1280, 1920};
  const float* CW[3] = {cw0, cw1, cw2};
  const float* CB[3] = {cb0, cb1, cb2};

  for (int li = 0; li < 3; ++li) {
    const int F = Fs[li];
    const float* Hi = hi + HOFF[li];
    const float* Hj = hj + HOFF[li];
    for (int p = t; p < 400; p += 256) {
      int r = p / 20, cq = p % 20;
      float a = 0.0f;
      for (int d = 0; d < F; ++d) a += Hi[r * F + d] * Hj[cq * F + d];
      sim[p] = a;
    }
    __syncthreads();
    if (t < 100) {
      int oy = t / 10, ox = t % 10;
      float cy = (oy + 0.5f) * (512.0f / 10.0f) - 0.5f;
      float cx = (ox + 0.5f) * (512.0f / 10.0f) - 0.5f;
      float fy = cy - floorf(cy);
      float fx = cx - floorf(cx);
      int r0 = 2 * oy, c0 = 2 * ox;
      float s00 = sim[r0 * 20 + c0], s01 = sim[r0 * 20 + c0 + 1];
      float s10 = sim[(r0 + 1) * 20 + c0], s11 = sim[(r0 + 1) * 20 + c0 + 1];
      simr[t] = (1.0f - fy) * ((1.0f - fx) * s00 + fx * s01) + fy * ((1.0f - fx) * s10 + fx * s11);
    }
    __syncthreads();
    const float* cw = CW[li];
    const float* cb = CB[li];
    for (int idx = t; idx < 800; idx += 256) {
      int cch = idx / 100, rem = idx % 100, y = rem / 10, x = rem % 10;
      float a = cb[cch];
#pragma unroll
      for (int ky = 0; ky < 3; ++ky) {
#pragma unroll
        for (int kx = 0; kx < 3; ++kx) {
          int iy = y + ky - 1, ix = x + kx - 1;
          if (iy >= 0 && iy < 10 && ix >= 0 && ix < 10)
            a += cw[cch * 9 + ky * 3 + kx] * simr[iy * 10 + ix];
        }
      }
      feat[li * 800 + idx] = fmaxf(a, 0.0f);
    }
    __syncthreads();
  }

  // MLP0: 2400 -> 32, 8 partial sums per output
  {
    int f = t & 31, part = t >> 5;
    float a = 0.0f;
    int k0 = part * 300;
    for (int k = k0; k < k0 + 300; ++k) a += feat[k] * mw0[k * 32 + f];
    red[t] = a;
    __syncthreads();
    if (t < 32) {
      float s = mb0[t];
#pragma unroll
      for (int p = 0; p < 8; ++p) s += red[p * 32 + t];
      mbuf[t] = fmaxf(s, 0.0f);
    }
    __syncthreads();
  }
  if (t < 16) {
    float s = mb1[t];
    for (int k = 0; k < 32; ++k) s += mbuf[k] * mw1[k * 16 + t];
    mbuf[32 + t] = fmaxf(s, 0.0f);
  }
  __syncthreads();
  if (t < 8) {
    float s = mb2[t];
    for (int k = 0; k < 16; ++k) s += mbuf[32 + k] * mw2[k * 8 + t];
    mbuf[48 + t] = fmaxf(s, 0.0f);
  }
  __syncthreads();
  if (t < 4) {
    float s = mb3[t];
    for (int k = 0; k < 8; ++k) s += mbuf[48 + k] * mw3[k * 4 + t];
    mbuf[56 + t] = fmaxf(s, 0.0f);
  }
  __syncthreads();
  if (t == 0) {
    float s = mb4[0];
    for (int k = 0; k < 4; ++k) s += mbuf[56 + k] * mw4[k];
    s = fmaxf(s, 0.0f);
    float z = s * sw[0] + sb[0];
    out[b] = 1.0f / (1.0f + expf(-z));
  }
}

extern "C" void kernel_launch(void* const* d_in, const int* in_sizes, int n_in,
                              void* d_out, int out_size, void* d_ws, size_t ws_size,
                              hipStream_t stream) {
  (void)in_sizes; (void)n_in; (void)out_size; (void)ws_size;
  const float* x_i = (const float*)d_in[0];
  const float* x_j = (const float*)d_in[1];
  const float* gw0 = (const float*)d_in[2];
  const float* gb0 = (const float*)d_in[3];
  const float* gw1 = (const float*)d_in[4];
  const float* gb1 = (const float*)d_in[5];
  const float* gw2 = (const float*)d_in[6];
  const float* gb2 = (const float*)d_in[7];
  const float* cw0 = (const float*)d_in[8];
  const float* cb0 = (const float*)d_in[9];
  const float* cw1 = (const float*)d_in[10];
  const float* cb1 = (const float*)d_in[11];
  const float* cw2 = (const float*)d_in[12];
  const float* cb2 = (const float*)d_in[13];
  const float* mw0 = (const float*)d_in[14];
  const float* mb0 = (const float*)d_in[15];
  const float* mw1 = (const float*)d_in[16];
  const float* mb1 = (const float*)d_in[17];
  const float* mw2 = (const float*)d_in[18];
  const float* mb2 = (const float*)d_in[19];
  const float* mw3 = (const float*)d_in[20];
  const float* mb3 = (const float*)d_in[21];
  const float* mw4 = (const float*)d_in[22];
  const float* mb4 = (const float*)d_in[23];
  const float* scw = (const float*)d_in[24];
  const float* scb = (const float*)d_in[25];
  const int* ei = (const int*)d_in[26];
  const int* ej = (const int*)d_in[27];
  float* out = (float*)d_out;

  char* p = (char*)d_ws;
  auto take = [&](size_t bytes) {
    char* r = p;
    p += (bytes + 255) & ~(size_t)255;
    return r;
  };
  float* hs0 = (float*)take((size_t)2 * BB * 20 * 64 * 4);
  float* hs1 = (float*)take((size_t)2 * BB * 20 * 32 * 4);
  float* hs2 = (float*)take((size_t)2 * BB * 20 * 16 * 4);

  k_all<<<2 * BB, 512, 0, stream>>>(x_i, x_j, gw0, gb0, gw1, gb1, gw2, gb2,
                                    ei, ej, hs0, hs1, hs2);
  k_head<<<BB, 256, 0, stream>>>(hs0, hs1, hs2, cw0, cb0, cw1, cb1, cw2, cb2,
                                 mw0, mb0, mw1, mb1, mw2, mb2, mw3, mb3, mw4, mb4,
                                 scw, scb, out);
}

// Round 13
// 130.451 us; speedup vs baseline: 1.5191x; 1.0789x over previous
//
#include <hip/hip_runtime.h>

typedef float fvec4 __attribute__((ext_vector_type(4)));

#define NN 65536      // total nodes per side (B*NPG)
#define EE 1048576    // edges per side (B*NPG*DEG)
#define BB 128
#define NPG 512
#define EPG 8192      // edges per graph (NPG*DEG)

// ---- one 32-float (NQ=8) or 16-float (NQ=4) publish+gather pass ----
// msgQ layout: row r = 32 words at r*32 (one full bank line); quad q of row r at
// slot (q + r) & 7. Per edge, the NQ reads hit distinct bank groups; for fixed q,
// random rows spread lanes uniformly over the 8 groups.
// sids holds packed keys: (lv<<3) | (lv&7) so base = key & ~7, (q+key)&7 = (q+lv)&7.
template <int NQ, int FOUT, int COFF, bool RELU, bool LAST>
__device__ __forceinline__ void pass32(const fvec4* acc, fvec4* o,
                                       const float* __restrict__ bias,
                                       int node, int start, int count, float inv_v, int slot,
                                       fvec4* __restrict__ msgQ, const int* __restrict__ sids,
                                       float* __restrict__ hs, int hb) {
  {
    const int rb = node << 3;
    const int m = node & 7;
#pragma unroll
    for (int q = 0; q < NQ; ++q) msgQ[rb | ((q + m) & 7)] = acc[q] * inv_v;
  }
  __syncthreads();
  if (!LAST || slot >= 0) {
    fvec4 s[NQ];
#pragma unroll
    for (int q = 0; q < NQ; ++q) s[q] = fvec4{0.f, 0.f, 0.f, 0.f};
    int e = start;
    const int end = start + count;
    for (; e + 2 <= end; e += 2) {
      const int k0 = sids[e], k1 = sids[e + 1];
      const int b0 = k0 & ~7, b1 = k1 & ~7;
#pragma unroll
      for (int q = 0; q < NQ; ++q) s[q] += msgQ[b0 | ((q + k0) & 7)];
#pragma unroll
      for (int q = 0; q < NQ; ++q) s[q] += msgQ[b1 | ((q + k1) & 7)];
    }
    if (e < end) {
      const int k0 = sids[e];
      const int b0 = k0 & ~7;
#pragma unroll
      for (int q = 0; q < NQ; ++q) s[q] += msgQ[b0 | ((q + k0) & 7)];
    }
    const float i2 = inv_v * inv_v;
#pragma unroll
    for (int q = 0; q < NQ; ++q) {
#pragma unroll
      for (int j = 0; j < 4; ++j) {
        float ov = s[q][j] * inv_v + acc[q][j] * i2 + bias[COFF + q * 4 + j];
        if (RELU) ov = fmaxf(ov, 0.f);
        o[q][j] = ov;
      }
    }
    if (slot >= 0) {
      fvec4* hp = reinterpret_cast<fvec4*>(hs + ((size_t)hb + slot) * FOUT + COFF);
#pragma unroll
      for (int q = 0; q < NQ; ++q) hp[q] = o[q];
    }
  }
  __syncthreads();
}

// ---------------- one block per (side, graph): CSR build + degree-sort + 3 GCN layers ----------------
__global__ __launch_bounds__(512)
void k_all(const float* __restrict__ x_i, const float* __restrict__ x_j,
           const float* __restrict__ gw0, const float* __restrict__ gb0,
           const float* __restrict__ gw1, const float* __restrict__ gb1,
           const float* __restrict__ gw2, const float* __restrict__ gb2,
           const int* __restrict__ ei, const int* __restrict__ ej,
           float* __restrict__ hs0, float* __restrict__ hs1, float* __restrict__ hs2) {
  __shared__ int sids[EPG];        // 32 KB: packed swizzle keys, bucketed by dst
  __shared__ fvec4 msgQ[NPG * 8];  // 64 KB: 32-float msg rows (aliases dsts in prep)
  __shared__ int cnt[NPG];
  __shared__ int posb[NPG];
  __shared__ int nodeOf[NPG];      // rank -> node (degree-sorted)
  __shared__ int bins[64];
  __shared__ int binpos[64];
  __shared__ int wsum[8];
  int* const dsts = reinterpret_cast<int*>(msgQ);  // prep-only staging

  const int side = blockIdx.x >> 7;
  const int g = blockIdx.x & 127;
  const float* __restrict__ x = side ? x_j : x_i;
  const int* __restrict__ eidx = side ? ej : ei;
  const int v = threadIdx.x;
  const int base = g * NPG;
  const int ebase = g * EPG;

  // ---- in-LDS degree count ----
  cnt[v] = 0;
  if (v < 64) bins[v] = 0;
  __syncthreads();
  for (int k = v; k < EPG; k += 512) {
    int d = eidx[EE + ebase + k] - base;
    dsts[k] = d;
    atomicAdd(&cnt[d], 1);
  }
  __syncthreads();

  // ---- in-block exclusive scan over 512 counts + degree histogram ----
  const int count = cnt[v];
  const int deg = count > 63 ? 63 : count;
  atomicAdd(&bins[deg], 1);
  int xa = count;
  const int lane = v & 63;
#pragma unroll
  for (int d = 1; d < 64; d <<= 1) {
    int y = __shfl_up(xa, d, 64);
    if (lane >= d) xa += y;
  }
  const int wid = v >> 6;
  if (lane == 63) wsum[wid] = xa;
  __syncthreads();
  if (v < 64) {  // wave 0: scan wsum (v==0) and bins (all 64 lanes)
    if (v == 0) {
      int a = 0;
#pragma unroll
      for (int i = 0; i < 8; ++i) { int tv = wsum[i]; wsum[i] = a; a += tv; }
    }
    int c = bins[v];
    int xb = c;
#pragma unroll
    for (int d = 1; d < 64; d <<= 1) {
      int y = __shfl_up(xb, d, 64);
      if (v >= d) xb += y;
    }
    binpos[v] = xb - c;
  }
  __syncthreads();
  const int start_v = xa - count + wsum[wid];
  posb[v] = start_v;
  {  // degree-sorted rank assignment
    int rank = atomicAdd(&binpos[deg], 1);
    nodeOf[rank] = v;
  }
  __syncthreads();

  // ---- CSR fill (bucket by dst), storing packed swizzle keys ----
  for (int k = v; k < EPG; k += 512) {
    int lv = eidx[ebase + k] - base;
    int p = atomicAdd(&posb[dsts[k]], 1);
    sids[p] = (lv << 3) | (lv & 7);
  }
  __syncthreads();

  // ---- this thread now owns node = nodeOf[v] (wave-uniform degrees) ----
  const int node = nodeOf[v];
  const int ncount = cnt[node];
  const int nstart = posb[node] - ncount;  // posb was bumped to end by fill
  const float inv_v = rsqrtf((float)ncount + 1.0f);

  // ---- sampled rows used by the bilinear-resized similarity image ----
  constexpr int srows[20] = {25, 26, 76, 77, 127, 128, 178, 179, 229, 230,
                             281, 282, 332, 333, 383, 384, 434, 435, 485, 486};
  int slot = -1;
#pragma unroll
  for (int i = 0; i < 20; ++i)
    if (node == srows[i]) slot = i;
  const int hb = (side * BB + g) * 20;

  // ---- layer 0: full xW0 row in one streaming pass over x ----
  fvec4 a0[16];
#pragma unroll
  for (int q = 0; q < 16; ++q) a0[q] = fvec4{0.f, 0.f, 0.f, 0.f};
  {
    const fvec4* xv = reinterpret_cast<const fvec4*>(x + (size_t)(base + node) * 64);
#pragma unroll 1
    for (int k16 = 0; k16 < 4; ++k16) {
      fvec4 xq[4];
#pragma unroll
      for (int u = 0; u < 4; ++u) xq[u] = xv[4 * k16 + u];
#pragma unroll
      for (int u = 0; u < 4; ++u) {
#pragma unroll
        for (int j = 0; j < 4; ++j) {
          const float xk = xq[u][j];
          const fvec4* wr = reinterpret_cast<const fvec4*>(gw0 + (size_t)(16 * k16 + 4 * u + j) * 64);
#pragma unroll
          for (int q = 0; q < 16; ++q) a0[q] += xk * wr[q];
        }
      }
    }
  }

  // ---- layer 0: two 32-wide passes; fold finished h0 halves into y1 = h0*W1 ----
  fvec4 y1[8];
  {
    fvec4 o[8];
    pass32<8, 64, 0, true, false>(&a0[0], o, gb0, node, nstart, ncount, inv_v, slot, msgQ, sids, hs0, hb);
#pragma unroll
    for (int q = 0; q < 8; ++q) y1[q] = fvec4{0.f, 0.f, 0.f, 0.f};
#pragma unroll
    for (int f = 0; f < 32; ++f) {
      const float hf = o[f >> 2][f & 3];
      const fvec4* wr = reinterpret_cast<const fvec4*>(gw1 + (size_t)f * 32);
#pragma unroll
      for (int q = 0; q < 8; ++q) y1[q] += hf * wr[q];
    }
  }
  {
    fvec4 o[8];
    pass32<8, 64, 32, true, false>(&a0[8], o, gb0, node, nstart, ncount, inv_v, slot, msgQ, sids, hs0, hb);
#pragma unroll
    for (int f = 0; f < 32; ++f) {
      const float hf = o[f >> 2][f & 3];
      const fvec4* wr = reinterpret_cast<const fvec4*>(gw1 + (size_t)(32 + f) * 32);
#pragma unroll
      for (int q = 0; q < 8; ++q) y1[q] += hf * wr[q];
    }
  }

  // ---- layer 1: one 32-wide pass; fold h1 into y2 = h1*W2 ----
  fvec4 y2[4];
  {
    fvec4 o[8];
    pass32<8, 32, 0, true, false>(y1, o, gb1, node, nstart, ncount, inv_v, slot, msgQ, sids, hs1, hb);
#pragma unroll
    for (int q = 0; q < 4; ++q) y2[q] = fvec4{0.f, 0.f, 0.f, 0.f};
#pragma unroll
    for (int f = 0; f < 32; ++f) {
      const float hf = o[f >> 2][f & 3];
      const fvec4* wr = reinterpret_cast<const fvec4*>(gw2 + (size_t)f * 16);
#pragma unroll
      for (int q = 0; q < 4; ++q) y2[q] += hf * wr[q];
    }
  }

  // ---- layer 2: one 16-wide pass; gather only for sampled rows ----
  {
    fvec4 o[4];
    pass32<4, 16, 0, false, true>(y2, o, gb2, node, nstart, ncount, inv_v, slot, msgQ, sids, hs2, hb);
  }
}

// ---------------- head: sampled sim -> bilinear 10x10 -> conv3x3(1->8) -> MLP -> sigmoid ----------------
__global__ __launch_bounds__(256) void k_head(const float* __restrict__ hs0, const float* __restrict__ hs1,
                                              const float* __restrict__ hs2,
                                              const float* __restrict__ cw0, const float* __restrict__ cb0,
                                              const float* __restrict__ cw1, const float* __restrict__ cb1,
                                              const float* __restrict__ cw2, const float* __restrict__ cb2,
                                              const float* __restrict__ mw0, const float* __restrict__ mb0,
                                              const float* __restrict__ mw1, const float* __restrict__ mb1,
                                              const float* __restrict__ mw2, const float* __restrict__ mb2,
                                              const float* __restrict__ mw3, const float* __restrict__ mb3,
                                              const float* __restrict__ mw4, const float* __restrict__ mb4,
                                              const float* __restrict__ sw, const float* __restrict__ sb,
                                              float* __restrict__ out) {
  __shared__ float hi[2240];  // 20*64 + 20*32 + 20*16
  __shared__ float hj[2240];
  __shared__ float sim[400];
  __shared__ float simr[100];
  __shared__ float feat[2400];
  __shared__ float red[256];
  __shared__ float mbuf[60];
  const int b = blockIdx.x, t = threadIdx.x;

  for (int k = t; k < 1280; k += 256) {
    hi[k] = hs0[(size_t)(0 * BB + b) * 1280 + k];
    hj[k] = hs0[(size_t)(1 * BB + b) * 1280 + k];
  }
  for (int k = t; k < 640; k += 256) {
    hi[1280 + k] = hs1[(size_t)(0 * BB + b) * 640 + k];
    hj[1280 + k] = hs1[(size_t)(1 * BB + b) * 640 + k];
  }
  for (int k = t; k < 320; k += 256) {
    hi[1920 + k] = hs2[(size_t)(0 * BB + b) * 320 + k];
    hj[1920 + k] = hs2[(size_t)(1 * BB + b) * 320 + k];
  }
  __syncthreads();

  const int Fs[3] = {64, 32, 16};
  const int HOFF[3] = {0, 1280, 1920};
  const float* CW[3] = {cw0, cw1, cw2};
  const float* CB[3] = {cb0, cb1, cb2};

  for (int li = 0; li < 3; ++li) {
    const int F = Fs[li];
    const float* Hi = hi + HOFF[li];
    const float* Hj = hj + HOFF[li];
    for (int p = t; p < 400; p += 256) {
      int r = p / 20, cq = p % 20;
      float a = 0.0f;
      for (int d = 0; d < F; ++d) a += Hi[r * F + d] * Hj[cq * F + d];
      sim[p] = a;
    }
    __syncthreads();
    if (t < 100) {
      int oy = t / 10, ox = t % 10;
      float cy = (oy + 0.5f) * (512.0f / 10.0f) - 0.5f;
      float cx = (ox + 0.5f) * (512.0f / 10.0f) - 0.5f;
      float fy = cy - floorf(cy);
      float fx = cx - floorf(cx);
      int r0 = 2 * oy, c0 = 2 * ox;
      float s00 = sim[r0 * 20 + c0], s01 = sim[r0 * 20 + c0 + 1];
      float s10 = sim[(r0 + 1) * 20 + c0], s11 = sim[(r0 + 1) * 20 + c0 + 1];
      simr[t] = (1.0f - fy) * ((1.0f - fx) * s00 + fx * s01) + fy * ((1.0f - fx) * s10 + fx * s11);
    }
    __syncthreads();
    const float* cw = CW[li];
    const float* cb = CB[li];
    for (int idx = t; idx < 800; idx += 256) {
      int cch = idx / 100, rem = idx % 100, y = rem / 10, x = rem % 10;
      float a = cb[cch];
#pragma unroll
      for (int ky = 0; ky < 3; ++ky) {
#pragma unroll
        for (int kx = 0; kx < 3; ++kx) {
          int iy = y + ky - 1, ix = x + kx - 1;
          if (iy >= 0 && iy < 10 && ix >= 0 && ix < 10)
            a += cw[cch * 9 + ky * 3 + kx] * simr[iy * 10 + ix];
        }
      }
      feat[li * 800 + idx] = fmaxf(a, 0.0f);
    }
    __syncthreads();
  }

  // MLP0: 2400 -> 32, 8 partial sums per output
  {
    int f = t & 31, part = t >> 5;
    float a = 0.0f;
    int k0 = part * 300;
    for (int k = k0; k < k0 + 300; ++k) a += feat[k] * mw0[k * 32 + f];
    red[t] = a;
    __syncthreads();
    if (t < 32) {
      float s = mb0[t];
#pragma unroll
      for (int p = 0; p < 8; ++p) s += red[p * 32 + t];
      mbuf[t] = fmaxf(s, 0.0f);
    }
    __syncthreads();
  }
  if (t < 16) {
    float s = mb1[t];
    for (int k = 0; k < 32; ++k) s += mbuf[k] * mw1[k * 16 + t];
    mbuf[32 + t] = fmaxf(s, 0.0f);
  }
  __syncthreads();
  if (t < 8) {
    float s = mb2[t];
    for (int k = 0; k < 16; ++k) s += mbuf[32 + k] * mw2[k * 8 + t];
    mbuf[48 + t] = fmaxf(s, 0.0f);
  }
  __syncthreads();
  if (t < 4) {
    float s = mb3[t];
    for (int k = 0; k < 8; ++k) s += mbuf[48 + k] * mw3[k * 4 + t];
    mbuf[56 + t] = fmaxf(s, 0.0f);
  }
  __syncthreads();
  if (t == 0) {
    float s = mb4[0];
    for (int k = 0; k < 4; ++k) s += mbuf[56 + k] * mw4[k];
    s = fmaxf(s, 0.0f);
    float z = s * sw[0] + sb[0];
    out[b] = 1.0f / (1.0f + expf(-z));
  }
}

extern "C" void kernel_launch(void* const* d_in, const int* in_sizes, int n_in,
                              void* d_out, int out_size, void* d_ws, size_t ws_size,
                              hipStream_t stream) {
  (void)in_sizes; (void)n_in; (void)out_size; (void)ws_size;
  const float* x_i = (const float*)d_in[0];
  const float* x_j = (const float*)d_in[1];
  const float* gw0 = (const float*)d_in[2];
  const float* gb0 = (const float*)d_in[3];
  const float* gw1 = (const float*)d_in[4];
  const float* gb1 = (const float*)d_in[5];
  const float* gw2 = (const float*)d_in[6];
  const float* gb2 = (const float*)d_in[7];
  const float* cw0 = (const float*)d_in[8];
  const float* cb0 = (const float*)d_in[9];
  const float* cw1 = (const float*)d_in[10];
  const float* cb1 = (const float*)d_in[11];
  const float* cw2 = (const float*)d_in[12];
  const float* cb2 = (const float*)d_in[13];
  const float* mw0 = (const float*)d_in[14];
  const float* mb0 = (const float*)d_in[15];
  const float* mw1 = (const float*)d_in[16];
  const float* mb1 = (const float*)d_in[17];
  const float* mw2 = (const float*)d_in[18];
  const float* mb2 = (const float*)d_in[19];
  const float* mw3 = (const float*)d_in[20];
  const float* mb3 = (const float*)d_in[21];
  const float* mw4 = (const float*)d_in[22];
  const float* mb4 = (const float*)d_in[23];
  const float* scw = (const float*)d_in[24];
  const float* scb = (const float*)d_in[25];
  const int* ei = (const int*)d_in[26];
  const int* ej = (const int*)d_in[27];
  float* out = (float*)d_out;

  char* p = (char*)d_ws;
  auto take = [&](size_t bytes) {
    char* r = p;
    p += (bytes + 255) & ~(size_t)255;
    return r;
  };
  float* hs0 = (float*)take((size_t)2 * BB * 20 * 64 * 4);
  float* hs1 = (float*)take((size_t)2 * BB * 20 * 32 * 4);
  float* hs2 = (float*)take((size_t)2 * BB * 20 * 16 * 4);

  k_all<<<2 * BB, 512, 0, stream>>>(x_i, x_j, gw0, gb0, gw1, gb1, gw2, gb2,
                                    ei, ej, hs0, hs1, hs2);
  k_head<<<BB, 256, 0, stream>>>(hs0, hs1, hs2, cw0, cb0, cw1, cb1, cw2, cb2,
                                 mw0, mb0, mw1, mb1, mw2, mb2, mw3, mb3, mw4, mb4,
                                 scw, scb, out);
}